// Round 16
// baseline (99.811 us; speedup 1.0000x reference)
//
#include <hip/hip_runtime.h>
#include <hip/hip_bf16.h>

// out[e,i] = sum_j (e@W1+b1)[e, i*16+j] * h[e,j]  +  (e@W2+b2)[e,i]
// One fp16 MFMA GEMM over K=576 per 16-edge tile (18x mfma_f32_16x16x32_f16).
// K-mapping (same placement function on A and B sides):
//   main block kk=0..15, slot s=(lane>>4)*8+t:  (d=s, j=kk)
//     A[r,s] = e[edge_r, s] * h[edge_r, kk]     B[s, i=r] = W1[s*256 + r*16 + kk]
//   block 16: A = e[edge, s],                   B = W2[s*16 + r]
//   block 17: s<16: A=h[edge,s], B=b1[r*16+s]; s==16: A=1, B=b2[r]; else 0
//     -> block-17 A is free: hP0-3 (g=0), hP4-7 (g=1), {1,0..} (g=2), 0 (g=3)
// R15 = R11 hot loop, but B-fragments in REGISTERS (R5-style build; R5 proved
//   88 VGPR total). ZERO __shared__, zero barriers. Rationale: the 18
//   ds_read_b128/tile cost ~216 LDS-pipe cyc/tile = ~35-44us chip-wide
//   serialization (m134: b128 ~12cyc) -- the unmeasured co-bottleneck since R6.
//   Occupancy beyond ~12-16 waves/CU proven worthless (R9/R13), so the LDS-B
//   "free VGPRs" rationale is void. W1 re-reads per wave (16KB) are L2-hits.
// NO launch_bounds min-waves (R7 spill), NO local arrays (R2 PromoteAlloca).

using f16x8  = __attribute__((ext_vector_type(8))) _Float16;
using f16x2  = __attribute__((ext_vector_type(2))) _Float16;
using fp16v2 = __attribute__((ext_vector_type(2))) __fp16;   // native cvt_pkrtz type
using f32x4  = __attribute__((ext_vector_type(4))) float;
using u32x4  = __attribute__((ext_vector_type(4))) unsigned int;

static __device__ __forceinline__ unsigned int pkrtz(float lo, float hi) {
    fp16v2 p = __builtin_amdgcn_cvt_pkrtz(lo, hi);
    return __builtin_bit_cast(unsigned int, p);
}
static __device__ __forceinline__ f16x2 u2h(unsigned int u) {
    return __builtin_bit_cast(f16x2, u);
}
static __device__ __forceinline__ unsigned int h2u(f16x2 h) {
    return __builtin_bit_cast(unsigned int, h);
}
static __device__ __forceinline__ unsigned int bperm(int baddr, unsigned int src) {
    return (unsigned int)__builtin_amdgcn_ds_bpermute(baddr, (int)src);
}

__global__ void __launch_bounds__(256) msg_kernel(
    const float* __restrict__ hptr, const float* __restrict__ eptr,
    const float* __restrict__ W1,   const float* __restrict__ b1,
    const float* __restrict__ W2,   const float* __restrict__ b2,
    float* __restrict__ out, int E)
{
    const int lane = threadIdx.x & 63;
    const int g    = lane >> 4;        // K-group (0..3); lane's d-range = [g*8, g*8+8)
    const int r    = lane & 15;        // A row (edge-in-tile) == B/D col (output i)

    // ---- B fragments in registers: edge-invariant, built once per wave ----
    // (R5-verified pattern: 18 x f16x8 + staging = 88 VGPR, no spill.
    //  W1 is 128KB -> L2-resident; per-wave re-read is 16KB of L2 hits.)
    f16x8 Bf[18];
    #pragma unroll
    for (int t = 0; t < 8; ++t) {
        const int d = g * 8 + t;
        const float4* wp = (const float4*)(W1 + (size_t)d * 256 + r * 16);
        const float4 w0 = wp[0], w1 = wp[1], w2 = wp[2], w3 = wp[3];
        Bf[ 0][t] = (_Float16)w0.x; Bf[ 1][t] = (_Float16)w0.y;
        Bf[ 2][t] = (_Float16)w0.z; Bf[ 3][t] = (_Float16)w0.w;
        Bf[ 4][t] = (_Float16)w1.x; Bf[ 5][t] = (_Float16)w1.y;
        Bf[ 6][t] = (_Float16)w1.z; Bf[ 7][t] = (_Float16)w1.w;
        Bf[ 8][t] = (_Float16)w2.x; Bf[ 9][t] = (_Float16)w2.y;
        Bf[10][t] = (_Float16)w2.z; Bf[11][t] = (_Float16)w2.w;
        Bf[12][t] = (_Float16)w3.x; Bf[13][t] = (_Float16)w3.y;
        Bf[14][t] = (_Float16)w3.z; Bf[15][t] = (_Float16)w3.w;
        Bf[16][t] = (_Float16)W2[d * 16 + r];
        float v;
        if (d < 16)       v = b1[r * 16 + d];
        else if (d == 16) v = b2[r];
        else              v = 0.0f;
        Bf[17][t] = (_Float16)v;
    }

    const int ntiles = (E + 15) >> 4;
    const int nwaves = (gridDim.x * blockDim.x) >> 6;
    const int wid    = (blockIdx.x * blockDim.x + threadIdx.x) >> 6;
    if (wid >= ntiles) return;

    // bpermute byte-addresses of the 4 lanes holding row r's h quarters
    const int ba0 = (r      ) << 2;
    const int ba1 = (r + 16 ) << 2;
    const int ba2 = (r + 32 ) << 2;
    const int ba3 = (r + 48 ) << 2;

    // 3 loads per tile: e (2x float4, lane's own 8 values), h (1x float4, quarter)
#define LOADT(T, E0, E1, H0) { \
        int tt = (T); if (tt >= ntiles) tt = ntiles - 1; \
        int cc = tt * 16 + r; if (cc >= E) cc = E - 1; \
        const float4* ep_ = (const float4*)(eptr + (size_t)cc * 32 + g * 8); \
        E0 = ep_[0]; E1 = ep_[1]; \
        H0 = *(const float4*)(hptr + (size_t)cc * 16 + g * 4); }

    // MB: broadcast one fp16 from packed pair (static HALF -> VOP3P op_sel),
    // 4x v_pk_mul_f16, 1 MFMA with register-resident B fragment.
#define MB(HPQ, HALF, KK, ACC) { \
        const f16x2 hv_ = u2h(HPQ); \
        const f16x2 hh_ = {hv_[HALF], hv_[HALF]}; \
        u32x4 u_ = {h2u(hh_ * u2h(eP0)), h2u(hh_ * u2h(eP1)), \
                    h2u(hh_ * u2h(eP2)), h2u(hh_ * u2h(eP3))}; \
        ACC = __builtin_amdgcn_mfma_f32_16x16x32_f16( \
            __builtin_bit_cast(f16x8, u_), Bf[KK], ACC, 0, 0, 0); }

    // ---- 1-stage pipeline ----
    float4 sE0, sE1, sH;
    int t = wid;
    LOADT(t, sE0, sE1, sH);

    while (true) {
        // convert staged f32 -> packed fp16 (waits on this tile's loads)
        const unsigned int eP0 = pkrtz(sE0.x, sE0.y), eP1 = pkrtz(sE0.z, sE0.w);
        const unsigned int eP2 = pkrtz(sE1.x, sE1.y), eP3 = pkrtz(sE1.z, sE1.w);
        const unsigned int hQ0 = pkrtz(sH.x, sH.y),   hQ1 = pkrtz(sH.z, sH.w);

        // staging regs consumed -> immediately issue next tile's loads
        LOADT(t + nwaves, sE0, sE1, sH);

        // rebuild full packed h row via crossbar pulls from the row's 4 lanes
        const unsigned int hP0 = bperm(ba0, hQ0), hP1 = bperm(ba0, hQ1);
        const unsigned int hP2 = bperm(ba1, hQ0), hP3 = bperm(ba1, hQ1);
        const unsigned int hP4 = bperm(ba2, hQ0), hP5 = bperm(ba2, hQ1);
        const unsigned int hP6 = bperm(ba3, hQ0), hP7 = bperm(ba3, hQ1);

        f32x4 acc0 = {0.0f, 0.0f, 0.0f, 0.0f};
        f32x4 acc1 = {0.0f, 0.0f, 0.0f, 0.0f};

        MB(hP0, 0,  0, acc0)
        MB(hP0, 1,  1, acc1)
        MB(hP1, 0,  2, acc0)
        MB(hP1, 1,  3, acc1)
        MB(hP2, 0,  4, acc0)
        MB(hP2, 1,  5, acc1)
        MB(hP3, 0,  6, acc0)
        MB(hP3, 1,  7, acc1)
        MB(hP4, 0,  8, acc0)
        MB(hP4, 1,  9, acc1)
        MB(hP5, 0, 10, acc0)
        MB(hP5, 1, 11, acc1)
        MB(hP6, 0, 12, acc0)
        MB(hP6, 1, 13, acc1)
        MB(hP7, 0, 14, acc0)
        MB(hP7, 1, 15, acc1)

        {   // block 16: A = packed e
            u32x4 u_ = {eP0, eP1, eP2, eP3};
            acc0 = __builtin_amdgcn_mfma_f32_16x16x32_f16(
                __builtin_bit_cast(f16x8, u_), Bf[16], acc0, 0, 0, 0);
        }
        {   // block 17: A = hP0-3 (g=0) / hP4-7 (g=1) / {1,0,..} (g=2) / 0 (g=3)
            const unsigned int a0 = (g == 0) ? hP0 : (g == 1) ? hP4
                                   : (g == 2) ? 0x00003C00u : 0u;
            const unsigned int a1 = (g == 0) ? hP1 : (g == 1) ? hP5 : 0u;
            const unsigned int a2 = (g == 0) ? hP2 : (g == 1) ? hP6 : 0u;
            const unsigned int a3 = (g == 0) ? hP3 : (g == 1) ? hP7 : 0u;
            u32x4 u_ = {a0, a1, a2, a3};
            acc1 = __builtin_amdgcn_mfma_f32_16x16x32_f16(
                __builtin_bit_cast(f16x8, u_), Bf[17], acc1, 0, 0, 0);
        }

        // D: col = r = i, row = g*4 + q = edge-in-tile
        const int rowbase = t * 16 + g * 4;
        float* op = out + (size_t)rowbase * 16 + r;
        const float s0 = acc0[0] + acc1[0], s1 = acc0[1] + acc1[1];
        const float s2 = acc0[2] + acc1[2], s3 = acc0[3] + acc1[3];
        if (rowbase + 3 < E) { op[0] = s0; op[16] = s1; op[32] = s2; op[48] = s3; }
        else {
            if (rowbase     < E) op[ 0] = s0;
            if (rowbase + 1 < E) op[16] = s1;
            if (rowbase + 2 < E) op[32] = s2;
        }

        t += nwaves;
        if (t >= ntiles) break;
    }

#undef MB
#undef LOADT
}

extern "C" void kernel_launch(void* const* d_in, const int* in_sizes, int n_in,
                              void* d_out, int out_size, void* d_ws, size_t ws_size,
                              hipStream_t stream) {
    const float* h  = (const float*)d_in[0];
    const float* e  = (const float*)d_in[1];
    const float* W1 = (const float*)d_in[2];
    const float* b1 = (const float*)d_in[3];
    const float* W2 = (const float*)d_in[4];
    const float* b2 = (const float*)d_in[5];
    float* out = (float*)d_out;

    const int E = in_sizes[0] / 16;   // h is [E,16]

    dim3 grid(2048), block(256);
    hipLaunchKernelGGL(msg_kernel, grid, block, 0, stream,
                       h, e, W1, b1, W2, b2, out, E);
}

// Round 17
// 77.346 us; speedup vs baseline: 1.2904x; 1.2904x over previous
//
#include <hip/hip_runtime.h>
#include <hip/hip_bf16.h>

// out[e,i] = sum_j (e@W1+b1)[e, i*16+j] * h[e,j]  +  (e@W2+b2)[e,i]
// One fp16 MFMA GEMM over K=576 per 16-edge tile (18x mfma_f32_16x16x32_f16).
// K-mapping (same placement function on A and B sides):
//   main block kk=0..15, slot s=(lane>>4)*8+t:  (d=s, j=kk)
//     A[r,s] = e[edge_r, s] * h[edge_r, kk]     B[s, i=r] = W1[s*256 + r*16 + kk]
//   block 16: A = e[edge, s],                   B = W2[s*16 + r]
//   block 17: s<16: A=h[edge,s], B=b1[r*16+s]; s==16: A=1, B=b2[r]; else 0
//     -> block-17 A is free: hP0-3 (g=0), hP4-7 (g=1), {1,0..} (g=2), 0 (g=3)
// R16 = R11 (best, 85.3us, 64 VGPR / 8-wave class) + NON-TEMPORAL stores:
//   output (100MB, never re-read) streams through L2/L3 evicting e/h (307MB
//   inputs vs 256MB L3 -> only ~half hit). nt stores skip allocation ->
//   more L3 capacity for the read stream. Single-mechanism change.
// NO launch_bounds min-waves (R7 spill), NO local arrays (R2 PromoteAlloca).

using f16x8  = __attribute__((ext_vector_type(8))) _Float16;
using f16x2  = __attribute__((ext_vector_type(2))) _Float16;
using fp16v2 = __attribute__((ext_vector_type(2))) __fp16;   // native cvt_pkrtz type
using f32x4  = __attribute__((ext_vector_type(4))) float;
using u32x4  = __attribute__((ext_vector_type(4))) unsigned int;

static __device__ __forceinline__ unsigned int pkrtz(float lo, float hi) {
    fp16v2 p = __builtin_amdgcn_cvt_pkrtz(lo, hi);
    return __builtin_bit_cast(unsigned int, p);
}
static __device__ __forceinline__ f16x2 u2h(unsigned int u) {
    return __builtin_bit_cast(f16x2, u);
}
static __device__ __forceinline__ unsigned int h2u(f16x2 h) {
    return __builtin_bit_cast(unsigned int, h);
}
static __device__ __forceinline__ unsigned short f2h_bits(float x) {
    _Float16 h = (_Float16)x;                 // RNE scalar cast (one-time build only)
    return __builtin_bit_cast(unsigned short, h);
}
static __device__ __forceinline__ unsigned int bperm(int baddr, unsigned int src) {
    return (unsigned int)__builtin_amdgcn_ds_bpermute(baddr, (int)src);
}

__global__ void __launch_bounds__(256) msg_kernel(
    const float* __restrict__ hptr, const float* __restrict__ eptr,
    const float* __restrict__ W1,   const float* __restrict__ b1,
    const float* __restrict__ W2,   const float* __restrict__ b2,
    float* __restrict__ out, int E)
{
    // B fragment store: [kk=0..17][lane=0..63][t=0..7] fp16, 18 KB.
    __shared__ __align__(16) unsigned short Bs[18 * 64 * 8];

    const int lane = threadIdx.x & 63;
    const int g    = lane >> 4;        // K-group (0..3); lane's d-range = [g*8, g*8+8)
    const int r    = lane & 15;        // A row (edge-in-tile) == B/D col (output i)
    const int wv   = threadIdx.x >> 6; // wave id: parallel B-build by t-pair

    // ---- build B in LDS: wave wv handles t = wv*2, wv*2+1 ----
    #pragma unroll
    for (int tq = 0; tq < 2; ++tq) {
        const int t = wv * 2 + tq;
        const int d = g * 8 + t;
        const float4* wp = (const float4*)(W1 + (size_t)d * 256 + r * 16);
        const float4 w0 = wp[0], w1 = wp[1], w2 = wp[2], w3 = wp[3];
        Bs[( 0*64 + lane)*8 + t] = f2h_bits(w0.x);
        Bs[( 1*64 + lane)*8 + t] = f2h_bits(w0.y);
        Bs[( 2*64 + lane)*8 + t] = f2h_bits(w0.z);
        Bs[( 3*64 + lane)*8 + t] = f2h_bits(w0.w);
        Bs[( 4*64 + lane)*8 + t] = f2h_bits(w1.x);
        Bs[( 5*64 + lane)*8 + t] = f2h_bits(w1.y);
        Bs[( 6*64 + lane)*8 + t] = f2h_bits(w1.z);
        Bs[( 7*64 + lane)*8 + t] = f2h_bits(w1.w);
        Bs[( 8*64 + lane)*8 + t] = f2h_bits(w2.x);
        Bs[( 9*64 + lane)*8 + t] = f2h_bits(w2.y);
        Bs[(10*64 + lane)*8 + t] = f2h_bits(w2.z);
        Bs[(11*64 + lane)*8 + t] = f2h_bits(w2.w);
        Bs[(12*64 + lane)*8 + t] = f2h_bits(w3.x);
        Bs[(13*64 + lane)*8 + t] = f2h_bits(w3.y);
        Bs[(14*64 + lane)*8 + t] = f2h_bits(w3.z);
        Bs[(15*64 + lane)*8 + t] = f2h_bits(w3.w);
        Bs[(16*64 + lane)*8 + t] = f2h_bits(W2[d * 16 + r]);
        float v;
        if (d < 16)       v = b1[r * 16 + d];
        else if (d == 16) v = b2[r];
        else              v = 0.0f;
        Bs[(17*64 + lane)*8 + t] = f2h_bits(v);
    }
    __syncthreads();   // only barrier in the kernel

    const int ntiles = (E + 15) >> 4;
    const int nwaves = (gridDim.x * blockDim.x) >> 6;
    const int wid    = (blockIdx.x * blockDim.x + threadIdx.x) >> 6;
    if (wid >= ntiles) return;

    const unsigned short* bsl = &Bs[lane * 8];   // per-lane base; block kk at +kk*512

    // bpermute byte-addresses of the 4 lanes holding row r's h quarters
    const int ba0 = (r      ) << 2;
    const int ba1 = (r + 16 ) << 2;
    const int ba2 = (r + 32 ) << 2;
    const int ba3 = (r + 48 ) << 2;

#define LDSB(KK) __builtin_bit_cast(f16x8, *reinterpret_cast<const u32x4*>(bsl + (KK) * 512))

    // 3 loads per tile: e (2x float4, lane's own 8 values), h (1x float4, quarter)
#define LOADT(T, E0, E1, H0) { \
        int tt = (T); if (tt >= ntiles) tt = ntiles - 1; \
        int cc = tt * 16 + r; if (cc >= E) cc = E - 1; \
        const float4* ep_ = (const float4*)(eptr + (size_t)cc * 32 + g * 8); \
        E0 = ep_[0]; E1 = ep_[1]; \
        H0 = *(const float4*)(hptr + (size_t)cc * 16 + g * 4); }

    // MB: broadcast one fp16 from packed pair (static HALF -> VOP3P op_sel),
    // 4x v_pk_mul_f16, 1 MFMA with rotated B fragment.
#define MB(HPQ, HALF, BF, ACC) { \
        const f16x2 hv_ = u2h(HPQ); \
        const f16x2 hh_ = {hv_[HALF], hv_[HALF]}; \
        u32x4 u_ = {h2u(hh_ * u2h(eP0)), h2u(hh_ * u2h(eP1)), \
                    h2u(hh_ * u2h(eP2)), h2u(hh_ * u2h(eP3))}; \
        ACC = __builtin_amdgcn_mfma_f32_16x16x32_f16( \
            __builtin_bit_cast(f16x8, u_), BF, ACC, 0, 0, 0); }

    // ---- 1-stage pipeline (64-VGPR class) ----
    float4 sE0, sE1, sH;
    int t = wid;
    LOADT(t, sE0, sE1, sH);

    while (true) {
        // B-frag preload (depth-2 rotation)
        f16x8 Fb0 = LDSB(0), Fb1 = LDSB(1);

        // convert staged f32 -> packed fp16 (waits on this tile's loads)
        const unsigned int eP0 = pkrtz(sE0.x, sE0.y), eP1 = pkrtz(sE0.z, sE0.w);
        const unsigned int eP2 = pkrtz(sE1.x, sE1.y), eP3 = pkrtz(sE1.z, sE1.w);
        const unsigned int hQ0 = pkrtz(sH.x, sH.y),   hQ1 = pkrtz(sH.z, sH.w);

        // staging regs consumed -> immediately issue next tile's loads
        LOADT(t + nwaves, sE0, sE1, sH);

        // rebuild full packed h row via crossbar pulls from the row's 4 lanes
        const unsigned int hP0 = bperm(ba0, hQ0), hP1 = bperm(ba0, hQ1);
        const unsigned int hP2 = bperm(ba1, hQ0), hP3 = bperm(ba1, hQ1);
        const unsigned int hP4 = bperm(ba2, hQ0), hP5 = bperm(ba2, hQ1);
        const unsigned int hP6 = bperm(ba3, hQ0), hP7 = bperm(ba3, hQ1);

        f32x4 acc0 = {0.0f, 0.0f, 0.0f, 0.0f};
        f32x4 acc1 = {0.0f, 0.0f, 0.0f, 0.0f};

        MB(hP0, 0, Fb0, acc0)  Fb0 = LDSB( 2);
        MB(hP0, 1, Fb1, acc1)  Fb1 = LDSB( 3);
        MB(hP1, 0, Fb0, acc0)  Fb0 = LDSB( 4);
        MB(hP1, 1, Fb1, acc1)  Fb1 = LDSB( 5);
        MB(hP2, 0, Fb0, acc0)  Fb0 = LDSB( 6);
        MB(hP2, 1, Fb1, acc1)  Fb1 = LDSB( 7);
        MB(hP3, 0, Fb0, acc0)  Fb0 = LDSB( 8);
        MB(hP3, 1, Fb1, acc1)  Fb1 = LDSB( 9);
        MB(hP4, 0, Fb0, acc0)  Fb0 = LDSB(10);
        MB(hP4, 1, Fb1, acc1)  Fb1 = LDSB(11);
        MB(hP5, 0, Fb0, acc0)  Fb0 = LDSB(12);
        MB(hP5, 1, Fb1, acc1)  Fb1 = LDSB(13);
        MB(hP6, 0, Fb0, acc0)  Fb0 = LDSB(14);
        MB(hP6, 1, Fb1, acc1)  Fb1 = LDSB(15);
        MB(hP7, 0, Fb0, acc0)  Fb0 = LDSB(16);
        MB(hP7, 1, Fb1, acc1)  Fb1 = LDSB(17);

        {   // block 16: A = packed e
            u32x4 u_ = {eP0, eP1, eP2, eP3};
            acc0 = __builtin_amdgcn_mfma_f32_16x16x32_f16(
                __builtin_bit_cast(f16x8, u_), Fb0, acc0, 0, 0, 0);
        }
        {   // block 17: A = hP0-3 (g=0) / hP4-7 (g=1) / {1,0,..} (g=2) / 0 (g=3)
            const unsigned int a0 = (g == 0) ? hP0 : (g == 1) ? hP4
                                   : (g == 2) ? 0x00003C00u : 0u;
            const unsigned int a1 = (g == 0) ? hP1 : (g == 1) ? hP5 : 0u;
            const unsigned int a2 = (g == 0) ? hP2 : (g == 1) ? hP6 : 0u;
            const unsigned int a3 = (g == 0) ? hP3 : (g == 1) ? hP7 : 0u;
            u32x4 u_ = {a0, a1, a2, a3};
            acc1 = __builtin_amdgcn_mfma_f32_16x16x32_f16(
                __builtin_bit_cast(f16x8, u_), Fb1, acc1, 0, 0, 0);
        }

        // D: col = r = i, row = g*4 + q = edge-in-tile. NON-TEMPORAL stores:
        // output is never re-read; don't let it evict e/h from L2/L3.
        const int rowbase = t * 16 + g * 4;
        float* op = out + (size_t)rowbase * 16 + r;
        const float s0 = acc0[0] + acc1[0], s1 = acc0[1] + acc1[1];
        const float s2 = acc0[2] + acc1[2], s3 = acc0[3] + acc1[3];
        if (rowbase + 3 < E) {
            __builtin_nontemporal_store(s0, op);
            __builtin_nontemporal_store(s1, op + 16);
            __builtin_nontemporal_store(s2, op + 32);
            __builtin_nontemporal_store(s3, op + 48);
        } else {
            if (rowbase     < E) __builtin_nontemporal_store(s0, op);
            if (rowbase + 1 < E) __builtin_nontemporal_store(s1, op + 16);
            if (rowbase + 2 < E) __builtin_nontemporal_store(s2, op + 32);
        }

        t += nwaves;
        if (t >= ntiles) break;
    }

#undef MB
#undef LOADT
#undef LDSB
}

extern "C" void kernel_launch(void* const* d_in, const int* in_sizes, int n_in,
                              void* d_out, int out_size, void* d_ws, size_t ws_size,
                              hipStream_t stream) {
    const float* h  = (const float*)d_in[0];
    const float* e  = (const float*)d_in[1];
    const float* W1 = (const float*)d_in[2];
    const float* b1 = (const float*)d_in[3];
    const float* W2 = (const float*)d_in[4];
    const float* b2 = (const float*)d_in[5];
    float* out = (float*)d_out;

    const int E = in_sizes[0] / 16;   // h is [E,16]

    dim3 grid(2048), block(256);
    hipLaunchKernelGGL(msg_kernel, grid, block, 0, stream,
                       h, e, W1, b1, W2, b2, out, E);
}